// Round 12
// baseline (116.864 us; speedup 1.0000x reference)
//
#include <hip/hip_runtime.h>

#define WW 512
#define HH 256
#define TS 48
#define NB 2
#define ZS 16                // z-rows marched per wave
#define KAPPA 0.01f
#define NU 0.01f

#define ROW(zz) (min(max((zz), 0), HH - 1) * WW)
#define LD4(p) (*reinterpret_cast<const float4*>(p))
#define LD2(p) (*reinterpret_cast<const float2*>(p))

__device__ __forceinline__ float elem(const float4 v, int e) {
    return e == 0 ? v.x : e == 1 ? v.y : e == 2 ? v.z : v.w;
}
__device__ __forceinline__ float4 f4add(const float4 a, const float4 b) {
    return make_float4(a.x + b.x, a.y + b.y, a.z + b.z, a.w + b.w);
}

// jnp.gradient first+second (gradient-of-gradient) along one axis, index i of n.
__device__ __forceinline__ void grad12(float fm2, float fm1, float fc, float fp1, float fp2,
                                       int i, int n, float invh, float& g, float& gg) {
    const float half = 0.5f * invh;
    if (i == 0) {
        g = (fp1 - fc) * invh;
        float g1 = (fp2 - fc) * half;
        gg = (g1 - g) * invh;
    } else if (i == n - 1) {
        g = (fc - fm1) * invh;
        float gm = (fc - fm2) * half;
        gg = (g - gm) * invh;
    } else {
        g = (fp1 - fm1) * half;
        float gim = (i == 1)     ? (fc - fm1) * invh : (fc - fm2) * half;
        float gip = (i == n - 2) ? (fp1 - fc) * invh : (fp2 - fc) * half;
        gg = (gip - gim) * half;
    }
}

__device__ __forceinline__ float grad1(float fm1, float fc, float fp1, int i, int n, float invh) {
    if (i == 0)     return (fp1 - fc) * invh;
    if (i == n - 1) return (fc - fm1) * invh;
    return (fp1 - fm1) * (0.5f * invh);
}

// 768 blocks x 256 threads (4 waves = 4 z-strips of 16, no barriers).
// XCD group g = bi&7 = (b, xh, zh): each XCD owns one z-half x x-half x batch
// for ALL 48 t -> t+-1 center rows are the XCD's own slice (L2-resident,
// ~2.9 MB live window < 4 MB), z-stencil entirely in registers (z-ring).
// Cache-transit: T/u/w x3 (ring + two t-neighbors), P x1 => 2.2x vs
// t-march's 4.2x -- attacks the measured ~12 TB/s L2 bandwidth wall.
__global__ __launch_bounds__(256) void rbc_loss_kernel(const float* __restrict__ pred,
                                                       double* __restrict__ dacc) {
    const int sT = HH * WW;          // 131072
    const int sC = TS * sT;
    const int sB = 5 * sC;

    const int bi = blockIdx.x;
    const int g     = bi & 7;        // XCD (hardware round-robins bi % 8)
    const int local = bi >> 3;       // 0..95 within XCD
    const int b  = g >> 2;
    const int xh = (g >> 1) & 1;
    const int zh = g & 1;
    const int t  = local >> 1;       // 0..47
    const int sg = local & 1;        // strip-group within z-half

    const int lane = threadIdx.x & 63, w = threadIdx.x >> 6;
    const int z0 = (zh << 7) + (sg << 6) + (w << 4);   // strip base
    const int x0 = (xh << 8) + (lane << 2);            // quad base

    const float invdt = TS / 10.0f;
    const float invdx = (float)(WW / 6.283185307179586);
    const float invdz = HH / 2.0f;

    const float* __restrict__ pT = pred + (size_t)b * sB + 0 * (size_t)sC;
    const float* __restrict__ pU = pred + (size_t)b * sB + 1 * (size_t)sC;
    const float* __restrict__ pV = pred + (size_t)b * sB + 2 * (size_t)sC;
    const float* __restrict__ q3 = pred + (size_t)b * sB + 3 * (size_t)sC;
    const float* __restrict__ q4 = pred + (size_t)b * sB + 4 * (size_t)sC;

    const size_t o = (size_t)t * sT;
    // t-clamped neighbor-plane bases (block-uniform)
    const float* __restrict__ pTm = pT + o - (t > 0      ? (size_t)sT : 0);
    const float* __restrict__ pTp = pT + o + (t < TS - 1 ? (size_t)sT : 0);
    const float* __restrict__ pUm = pU + o - (t > 0      ? (size_t)sT : 0);
    const float* __restrict__ pUp = pU + o + (t < TS - 1 ? (size_t)sT : 0);
    const float* __restrict__ pVm = pV + o - (t > 0      ? (size_t)sT : 0);
    const float* __restrict__ pVp = pV + o + (t < TS - 1 ? (size_t)sT : 0);

    // seam between x-halves (x=255|256); global x-edges handled by grad12 branches
    const bool isR = (lane == 63) && (xh == 0);   // needs x=256,257
    const bool isL = (lane == 0)  && (xh == 1);   // needs x=254,255
    const int sOff  = isR ? 256 : 254;
    const int sPOff = isR ? 256 : 255;

    // ---- z-ring warm-up (clamped rows feed only grad12 edge branches) ----
    float4 Tzm2 = LD4(pT + o + ROW(z0 - 2) + x0), Tzm1 = LD4(pT + o + ROW(z0 - 1) + x0);
    float4 Tzc  = LD4(pT + o + ROW(z0)     + x0), Tzp1 = LD4(pT + o + ROW(z0 + 1) + x0);
    float4 Uzm2 = LD4(pU + o + ROW(z0 - 2) + x0), Uzm1 = LD4(pU + o + ROW(z0 - 1) + x0);
    float4 Uzc  = LD4(pU + o + ROW(z0)     + x0), Uzp1 = LD4(pU + o + ROW(z0 + 1) + x0);
    float4 Vzm2 = LD4(pV + o + ROW(z0 - 2) + x0), Vzm1 = LD4(pV + o + ROW(z0 - 1) + x0);
    float4 Vzc  = LD4(pV + o + ROW(z0)     + x0), Vzp1 = LD4(pV + o + ROW(z0 + 1) + x0);
    float4 Pm1 = f4add(LD4(q3 + o + ROW(z0 - 1) + x0), LD4(q4 + o + ROW(z0 - 1) + x0));
    float4 Pc  = f4add(LD4(q3 + o + ROW(z0)     + x0), LD4(q4 + o + ROW(z0)     + x0));

    float acc = 0.f;

    #pragma unroll 1
    for (int z = z0; z < z0 + ZS; ++z) {
        const int rowC = z * WW;
        const int rP1 = ROW(z + 1), rP2 = ROW(z + 2);

        // ---- loads in consumption order ----
        float4 B3  = LD4(q3 + o + rP1 + x0);            // P ring advance
        float4 B4  = LD4(q4 + o + rP1 + x0);
        float4 TzI = LD4(pT + o + rP2 + x0);            // T/U/V ring advance
        float4 UzI = LD4(pU + o + rP2 + x0);
        float4 VzI = LD4(pV + o + rP2 + x0);
        float2 Tse = make_float2(0.f, 0.f), Use = Tse, Vse = Tse; float Pse = 0.f;
        if (isR | isL) {                                 // seam (2 lanes, masked)
            Tse = LD2(pT + o + rowC + sOff);
            Use = LD2(pU + o + rowC + sOff);
            Vse = LD2(pV + o + rowC + sOff);
            Pse = q3[o + rowC + sPOff] + q4[o + rowC + sPOff];
        }
        float4 Ttm = LD4(pTm + rowC + x0), Ttp = LD4(pTp + rowC + x0);  // t+-1
        float4 Utm = LD4(pUm + rowC + x0), Utp = LD4(pUp + rowC + x0);
        float4 Vtm = LD4(pVm + rowC + x0), Vtp = LD4(pVp + rowC + x0);

        float4 Pp1 = f4add(B3, B4);

        // x-neighbors from ring registers via shuffles (no memory wait)
        float Tl2 = __shfl_up(Tzc.z, 1),   Tl3 = __shfl_up(Tzc.w, 1);
        float Tr0 = __shfl_down(Tzc.x, 1), Tr1 = __shfl_down(Tzc.y, 1);
        float Ul2 = __shfl_up(Uzc.z, 1),   Ul3 = __shfl_up(Uzc.w, 1);
        float Ur0 = __shfl_down(Uzc.x, 1), Ur1 = __shfl_down(Uzc.y, 1);
        float Vl2 = __shfl_up(Vzc.z, 1),   Vl3 = __shfl_up(Vzc.w, 1);
        float Vr0 = __shfl_down(Vzc.x, 1), Vr1 = __shfl_down(Vzc.y, 1);
        float Pl3 = __shfl_up(Pc.w, 1),    Pr0 = __shfl_down(Pc.x, 1);

        if (isR) { Tr0 = Tse.x; Tr1 = Tse.y; Ur0 = Use.x; Ur1 = Use.y;
                   Vr0 = Vse.x; Vr1 = Vse.y; Pr0 = Pse; }
        if (isL) { Tl2 = Tse.x; Tl3 = Tse.y; Ul2 = Use.x; Ul3 = Use.y;
                   Vl2 = Vse.x; Vl3 = Vse.y; Pl3 = Pse; }

        #pragma unroll
        for (int e = 0; e < 4; ++e) {
            const int i = x0 + e;
            const float txm2 = e == 0 ? Tl2 : e == 1 ? Tl3 : elem(Tzc, e - 2);
            const float txm1 = e == 0 ? Tl3 : elem(Tzc, e - 1);
            const float txc  = elem(Tzc, e);
            const float txp1 = e == 3 ? Tr0 : elem(Tzc, e + 1);
            const float txp2 = e == 2 ? Tr0 : e == 3 ? Tr1 : elem(Tzc, e + 2);
            const float uxm2 = e == 0 ? Ul2 : e == 1 ? Ul3 : elem(Uzc, e - 2);
            const float uxm1 = e == 0 ? Ul3 : elem(Uzc, e - 1);
            const float uxc  = elem(Uzc, e);
            const float uxp1 = e == 3 ? Ur0 : elem(Uzc, e + 1);
            const float uxp2 = e == 2 ? Ur0 : e == 3 ? Ur1 : elem(Uzc, e + 2);
            const float vxm2 = e == 0 ? Vl2 : e == 1 ? Vl3 : elem(Vzc, e - 2);
            const float vxm1 = e == 0 ? Vl3 : elem(Vzc, e - 1);
            const float vxc  = elem(Vzc, e);
            const float vxp1 = e == 3 ? Vr0 : elem(Vzc, e + 1);
            const float vxp2 = e == 2 ? Vr0 : e == 3 ? Vr1 : elem(Vzc, e + 2);
            const float pxm1 = e == 0 ? Pl3 : elem(Pc, e - 1);
            const float pxc  = elem(Pc, e);
            const float pxp1 = e == 3 ? Pr0 : elem(Pc, e + 1);

            // x-grads first (ring regs only), then P, z (ring), dt (loads)
            float dTdx, dTdxx, dTdz, dTdzz;
            grad12(txm2, txm1, txc, txp1, txp2, i, WW, invdx, dTdx, dTdxx);
            float dUdx, dUdxx, dUdz, dUdzz;
            grad12(uxm2, uxm1, uxc, uxp1, uxp2, i, WW, invdx, dUdx, dUdxx);
            float dVdx, dVdxx, dVdz, dVdzz;
            grad12(vxm2, vxm1, vxc, vxp1, vxp2, i, WW, invdx, dVdx, dVdxx);

            float dPdx = grad1(pxm1, pxc, pxp1, i, WW, invdx);
            float dPdz = grad1(elem(Pm1, e), pxc, elem(Pp1, e), z, HH, invdz);

            grad12(elem(Tzm2, e), elem(Tzm1, e), txc, elem(Tzp1, e), elem(TzI, e), z, HH, invdz, dTdz, dTdzz);
            grad12(elem(Uzm2, e), elem(Uzm1, e), uxc, elem(Uzp1, e), elem(UzI, e), z, HH, invdz, dUdz, dUdzz);
            grad12(elem(Vzm2, e), elem(Vzm1, e), vxc, elem(Vzp1, e), elem(VzI, e), z, HH, invdz, dVdz, dVdzz);

            float dTdt, dUdt, dVdt;   // t is block-uniform
            if (t == 0) {
                dTdt = (elem(Ttp, e) - txc) * invdt;
                dUdt = (elem(Utp, e) - uxc) * invdt;
                dVdt = (elem(Vtp, e) - vxc) * invdt;
            } else if (t == TS - 1) {
                dTdt = (txc - elem(Ttm, e)) * invdt;
                dUdt = (uxc - elem(Utm, e)) * invdt;
                dVdt = (vxc - elem(Vtm, e)) * invdt;
            } else {
                dTdt = (elem(Ttp, e) - elem(Ttm, e)) * (0.5f * invdt);
                dUdt = (elem(Utp, e) - elem(Utm, e)) * (0.5f * invdt);
                dVdt = (elem(Vtp, e) - elem(Vtm, e)) * (0.5f * invdt);
            }

            float dv = dUdx + dVdz;
            float te = dTdt + uxc * dTdx + vxc * dTdz - KAPPA * (dTdxx + dTdzz);
            float xm = dUdt + uxc * dUdx + vxc * dUdz + dPdx - NU * (dUdxx + dUdzz);
            float zm = dVdt + uxc * dVdx + vxc * dVdz + dPdz - NU * (dVdxx + dVdzz) - txc;

            acc += dv * dv + te * te + xm * xm + zm * zm;
        }

        // shift rings
        Tzm2 = Tzm1; Tzm1 = Tzc; Tzc = Tzp1; Tzp1 = TzI;
        Uzm2 = Uzm1; Uzm1 = Uzc; Uzc = Uzp1; Uzp1 = UzI;
        Vzm2 = Vzm1; Vzm1 = Vzc; Vzc = Vzp1; Vzp1 = VzI;
        Pm1 = Pc; Pc = Pp1;
    }

    // per-wave reduce + one atomic per wave (no LDS, no barrier)
    #pragma unroll
    for (int off = 32; off; off >>= 1) acc += __shfl_down(acc, off, 64);
    if (lane == 0) atomicAdd(dacc, (double)acc);
}

__global__ void rbc_finalize(const double* __restrict__ dacc, float* __restrict__ out) {
    const double N = (double)NB * TS * HH * WW;   // 12,582,912
    out[0] = (float)(dacc[0] / N);
}

extern "C" void kernel_launch(void* const* d_in, const int* in_sizes, int n_in,
                              void* d_out, int out_size, void* d_ws, size_t ws_size,
                              hipStream_t stream) {
    const float* pred = (const float*)d_in[0];
    double* dacc = (double*)d_ws;
    hipMemsetAsync(dacc, 0, sizeof(double), stream);

    const int nblocks = 8 * 48 * 2;   // 768 blocks x 256 threads = 12 waves/CU
    rbc_loss_kernel<<<nblocks, 256, 0, stream>>>(pred, dacc);
    rbc_finalize<<<1, 1, 0, stream>>>(dacc, (float*)d_out);
}

// Round 13
// 84.669 us; speedup vs baseline: 1.3803x; 1.3803x over previous
//
#include <hip/hip_runtime.h>

#define WW 512
#define HH 256
#define TS 48
#define NB 2
#define TCH 12               // t-steps per block
#define NCH (TS / TCH)       // 4 chunks
#define KAPPA 0.01f
#define NU 0.01f

#define ROW(zz) (min(max((zz), 0), HH - 1) * WW)
#define LD2(p) (*reinterpret_cast<const float2*>(p))

__device__ __forceinline__ float2 f2add(const float2 a, const float2 b) {
    return make_float2(a.x + b.x, a.y + b.y);
}

// jnp.gradient first+second (gradient-of-gradient) along one axis, index i of n.
__device__ __forceinline__ void grad12(float fm2, float fm1, float fc, float fp1, float fp2,
                                       int i, int n, float invh, float& g, float& gg) {
    const float half = 0.5f * invh;
    if (i == 0) {
        g = (fp1 - fc) * invh;
        float g1 = (fp2 - fc) * half;
        gg = (g1 - g) * invh;
    } else if (i == n - 1) {
        g = (fc - fm1) * invh;
        float gm = (fc - fm2) * half;
        gg = (g - gm) * invh;
    } else {
        g = (fp1 - fm1) * half;
        float gim = (i == 1)     ? (fc - fm1) * invh : (fc - fm2) * half;
        float gip = (i == n - 2) ? (fp1 - fc) * invh : (fp2 - fc) * half;
        gg = (gip - gim) * half;
    }
}

__device__ __forceinline__ float grad1(float fm1, float fc, float fp1, int i, int n, float invh) {
    if (i == 0)     return (fp1 - fc) * invh;
    if (i == n - 1) return (fc - fm1) * invh;
    return (fp1 - fm1) * (0.5f * invh);
}

// t-march, 2 z-rows per thread (rows A=2zp, B=2zp+1), 2 x per thread.
// z-stencil sharing: A's z+1 is B's center ring reg; halo = only 4 rows
// (zA-2, zA-1, zB+1, zB+2); P rows shared (4 instead of 6).
// 26 float2 loads / 4 points = 52 B/pt of L1<->L2 transit (1.62x cut vs 84).
__global__ __launch_bounds__(256) void rbc_loss_kernel(const float* __restrict__ pred,
                                                       double* __restrict__ dacc) {
    const int sT = HH * WW;          // 131072
    const int sC = TS * sT;
    const int sB = 5 * sC;

    // XCD-chunked swizzle: 1024 blocks, 128/XCD = one (b,tc) full-z sweep.
    const int bi = blockIdx.x;
    const int n  = (bi & 7) * (gridDim.x >> 3) + (bi >> 3);

    const int zp = n & 127;               // z-pair index
    const int tc = (n >> 7) & (NCH - 1);
    const int b  = n >> 9;
    const int t0 = tc * TCH;

    const int lane = threadIdx.x & 63, w = threadIdx.x >> 6;
    const int x0 = threadIdx.x << 1;      // pair base, 0..510 (block = full row)
    const int zA = zp << 1, zB = zA | 1;

    const float invdt = TS / 10.0f;
    const float invdx = (float)(WW / 6.283185307179586);
    const float invdz = HH / 2.0f;

    const float* __restrict__ pT = pred + (size_t)b * sB + 0 * (size_t)sC;
    const float* __restrict__ pU = pred + (size_t)b * sB + 1 * (size_t)sC;
    const float* __restrict__ pV = pred + (size_t)b * sB + 2 * (size_t)sC;
    const float* __restrict__ q3 = pred + (size_t)b * sB + 3 * (size_t)sC;
    const float* __restrict__ q4 = pred + (size_t)b * sB + 4 * (size_t)sC;

    const int rA = zA * WW + x0, rB = zB * WW + x0;
    const int rAm2 = ROW(zA - 2) + x0, rAm1 = ROW(zA - 1) + x0;
    const int rBp1 = ROW(zB + 1) + x0, rBp2 = ROW(zB + 2) + x0;

    // wave-seam lanes (x halo beyond shuffle range); grid x-edges use grad12 branches
    const bool needL = (lane == 0)  && (x0 != 0);
    const bool needR = (lane == 63) && (x0 != 510);
    const int sX  = needL ? x0 - 2 : x0 + 2;   // float2 covers both needed x
    const int sPX = needL ? x0 - 1 : x0 + 2;

    // ---- t-ring warm-up (planes t0-1 clamped, t0) for both rows ----
    const size_t op0 = (size_t)max(t0 - 1, 0) * sT;
    const size_t oc0 = (size_t)t0 * sT;
    float2 TpA = LD2(pT + op0 + rA), TpB = LD2(pT + op0 + rB);
    float2 UpA = LD2(pU + op0 + rA), UpB = LD2(pU + op0 + rB);
    float2 VpA = LD2(pV + op0 + rA), VpB = LD2(pV + op0 + rB);
    float2 TcA = LD2(pT + oc0 + rA), TcB = LD2(pT + oc0 + rB);
    float2 UcA = LD2(pU + oc0 + rA), UcB = LD2(pU + oc0 + rB);
    float2 VcA = LD2(pV + oc0 + rA), VcB = LD2(pV + oc0 + rB);

    float acc = 0.f;

// per-row compute: centers (Tc,Uc,Vc), t-ring (Tp,Tn), z-stencil (m2,m1,p1,p2),
// P (pm1,pc,pp1), seam regs, z-coordinate
#define ROWC(TcR, UcR, VcR, TpR, UpR, VpR, TnR, UnR, VnR,                         \
             TZ2, TZ1, TQ1, TQ2, UZ2, UZ1, UQ1, UQ2, VZ2, VZ1, VQ1, VQ2,          \
             Pm1v, Pcv, Pp1v, TsR, UsR, VsR, PsR, zc) do {                        \
    float TLx = __shfl_up(TcR.x, 1),   TLy = __shfl_up(TcR.y, 1);                 \
    float TRx = __shfl_down(TcR.x, 1), TRy = __shfl_down(TcR.y, 1);               \
    float ULx = __shfl_up(UcR.x, 1),   ULy = __shfl_up(UcR.y, 1);                 \
    float URx = __shfl_down(UcR.x, 1), URy = __shfl_down(UcR.y, 1);               \
    float VLx = __shfl_up(VcR.x, 1),   VLy = __shfl_up(VcR.y, 1);                 \
    float VRx = __shfl_down(VcR.x, 1), VRy = __shfl_down(VcR.y, 1);               \
    float PLy = __shfl_up(Pcv.y, 1),   PRx = __shfl_down(Pcv.x, 1);               \
    if (needL) { TLx = TsR.x; TLy = TsR.y; ULx = UsR.x; ULy = UsR.y;              \
                 VLx = VsR.x; VLy = VsR.y; PLy = PsR; }                           \
    if (needR) { TRx = TsR.x; TRy = TsR.y; URx = UsR.x; URy = UsR.y;              \
                 VRx = VsR.x; VRy = VsR.y; PRx = PsR; }                           \
    _Pragma("unroll")                                                             \
    for (int e = 0; e < 2; ++e) {                                                 \
        const int i = x0 + e;                                                     \
        const float txm2 = e ? TLy : TLx, txm1 = e ? TcR.x : TLy;                 \
        const float txc  = e ? TcR.y : TcR.x;                                     \
        const float txp1 = e ? TRx : TcR.y, txp2 = e ? TRy : TRx;                 \
        const float uxm2 = e ? ULy : ULx, uxm1 = e ? UcR.x : ULy;                 \
        const float uxc  = e ? UcR.y : UcR.x;                                     \
        const float uxp1 = e ? URx : UcR.y, uxp2 = e ? URy : URx;                 \
        const float vxm2 = e ? VLy : VLx, vxm1 = e ? VcR.x : VLy;                 \
        const float vxc  = e ? VcR.y : VcR.x;                                     \
        const float vxp1 = e ? VRx : VcR.y, vxp2 = e ? VRy : VRx;                 \
        const float pxm1 = e ? Pcv.x : PLy;                                       \
        const float pxc  = e ? Pcv.y : Pcv.x;                                     \
        const float pxp1 = e ? PRx : Pcv.y;                                       \
        float dTdx, dTdxx, dTdz, dTdzz;                                           \
        grad12(txm2, txm1, txc, txp1, txp2, i, WW, invdx, dTdx, dTdxx);           \
        float dUdx, dUdxx, dUdz, dUdzz;                                           \
        grad12(uxm2, uxm1, uxc, uxp1, uxp2, i, WW, invdx, dUdx, dUdxx);           \
        float dVdx, dVdxx, dVdz, dVdzz;                                           \
        grad12(vxm2, vxm1, vxc, vxp1, vxp2, i, WW, invdx, dVdx, dVdxx);           \
        float dPdx = grad1(pxm1, pxc, pxp1, i, WW, invdx);                        \
        const float pzm1 = e ? Pm1v.y : Pm1v.x, pzp1 = e ? Pp1v.y : Pp1v.x;       \
        float dPdz = grad1(pzm1, pxc, pzp1, zc, HH, invdz);                       \
        grad12(e ? TZ2.y : TZ2.x, e ? TZ1.y : TZ1.x, txc,                         \
               e ? TQ1.y : TQ1.x, e ? TQ2.y : TQ2.x, zc, HH, invdz, dTdz, dTdzz); \
        grad12(e ? UZ2.y : UZ2.x, e ? UZ1.y : UZ1.x, uxc,                         \
               e ? UQ1.y : UQ1.x, e ? UQ2.y : UQ2.x, zc, HH, invdz, dUdz, dUdzz); \
        grad12(e ? VZ2.y : VZ2.x, e ? VZ1.y : VZ1.x, vxc,                         \
               e ? VQ1.y : VQ1.x, e ? VQ2.y : VQ2.x, zc, HH, invdz, dVdz, dVdzz); \
        const float tpv = e ? TpR.y : TpR.x, tnv = e ? TnR.y : TnR.x;             \
        const float upv = e ? UpR.y : UpR.x, unv = e ? UnR.y : UnR.x;             \
        const float vpv = e ? VpR.y : VpR.x, vnv = e ? VnR.y : VnR.x;             \
        float dTdt, dUdt, dVdt;                                                   \
        if (t == 0) {                                                             \
            dTdt = (tnv - txc) * invdt;                                           \
            dUdt = (unv - uxc) * invdt;                                           \
            dVdt = (vnv - vxc) * invdt;                                           \
        } else if (t == TS - 1) {                                                 \
            dTdt = (txc - tpv) * invdt;                                           \
            dUdt = (uxc - upv) * invdt;                                           \
            dVdt = (vxc - vpv) * invdt;                                           \
        } else {                                                                  \
            dTdt = (tnv - tpv) * (0.5f * invdt);                                  \
            dUdt = (unv - upv) * (0.5f * invdt);                                  \
            dVdt = (vnv - vpv) * (0.5f * invdt);                                  \
        }                                                                         \
        float dv = dUdx + dVdz;                                                   \
        float te = dTdt + uxc * dTdx + vxc * dTdz - KAPPA * (dTdxx + dTdzz);      \
        float xm = dUdt + uxc * dUdx + vxc * dUdz + dPdx - NU * (dUdxx + dUdzz);  \
        float zm = dVdt + uxc * dVdx + vxc * dVdz + dPdz - NU * (dVdxx + dVdzz) - txc; \
        acc += dv * dv + te * te + xm * xm + zm * zm;                             \
    }                                                                             \
} while (0)

    #pragma unroll 1
    for (int t = t0; t < t0 + TCH; ++t) {
        const size_t o  = (size_t)t * sT;
        const size_t on = (size_t)min(t + 1, TS - 1) * sT;

        // ---- loads in consumption order ----
        // P rows (4 rows x 2 arrays, summed)
        float2 PmA = f2add(LD2(q3 + o + rAm1), LD2(q4 + o + rAm1));
        float2 PA  = f2add(LD2(q3 + o + rA),   LD2(q4 + o + rA));
        float2 PB  = f2add(LD2(q3 + o + rB),   LD2(q4 + o + rB));
        float2 PpB = f2add(LD2(q3 + o + rBp1), LD2(q4 + o + rBp1));
        // z-halo rows (4 rows x 3 ch) -- rows between are center ring regs
        float2 Tm2 = LD2(pT + o + rAm2), Tm1 = LD2(pT + o + rAm1);
        float2 Tq1 = LD2(pT + o + rBp1), Tq2 = LD2(pT + o + rBp2);
        float2 Um2 = LD2(pU + o + rAm2), Um1 = LD2(pU + o + rAm1);
        float2 Uq1 = LD2(pU + o + rBp1), Uq2 = LD2(pU + o + rBp2);
        float2 Vm2 = LD2(pV + o + rAm2), Vm1 = LD2(pV + o + rAm1);
        float2 Vq1 = LD2(pV + o + rBp1), Vq2 = LD2(pV + o + rBp2);
        // seam fixups (2 lanes/wave, both rows)
        float2 TsA = make_float2(0.f, 0.f), TsB = TsA, UsA = TsA, UsB = TsA,
               VsA = TsA, VsB = TsA;
        float PsA = 0.f, PsB = 0.f;
        if (needL | needR) {
            TsA = LD2(pT + o + zA * WW + sX); TsB = LD2(pT + o + zB * WW + sX);
            UsA = LD2(pU + o + zA * WW + sX); UsB = LD2(pU + o + zB * WW + sX);
            VsA = LD2(pV + o + zA * WW + sX); VsB = LD2(pV + o + zB * WW + sX);
            PsA = q3[o + zA * WW + sPX] + q4[o + zA * WW + sPX];
            PsB = q3[o + zB * WW + sPX] + q4[o + zB * WW + sPX];
        }
        // t+1 centers last (ring advance; consumed by dt then shift)
        float2 TnA = LD2(pT + on + rA), TnB = LD2(pT + on + rB);
        float2 UnA = LD2(pU + on + rA), UnB = LD2(pU + on + rB);
        float2 VnA = LD2(pV + on + rA), VnB = LD2(pV + on + rB);

        // row A: z-stencil = {Tm2, Tm1, [TcA], TcB, Tq1}; P = {PmA, PA, PB}
        ROWC(TcA, UcA, VcA, TpA, UpA, VpA, TnA, UnA, VnA,
             Tm2, Tm1, TcB, Tq1, Um2, Um1, UcB, Uq1, Vm2, Vm1, VcB, Vq1,
             PmA, PA, PB, TsA, UsA, VsA, PsA, zA);
        // row B: z-stencil = {Tm1, TcA, [TcB], Tq1, Tq2}; P = {PA, PB, PpB}
        ROWC(TcB, UcB, VcB, TpB, UpB, VpB, TnB, UnB, VnB,
             Tm1, TcA, Tq1, Tq2, Um1, UcA, Uq1, Uq2, Vm1, VcA, Vq1, Vq2,
             PA, PB, PpB, TsB, UsB, VsB, PsB, zB);

        // ring shift
        TpA = TcA; TcA = TnA; TpB = TcB; TcB = TnB;
        UpA = UcA; UcA = UnA; UpB = UcB; UcB = UnB;
        VpA = VcA; VcA = VnA; VpB = VcB; VcB = VnB;
    }

    // block reduction: wave shfl -> LDS -> one double atomic per block
    #pragma unroll
    for (int off = 32; off; off >>= 1) acc += __shfl_down(acc, off, 64);
    __shared__ float wsum[4];
    if (lane == 0) wsum[w] = acc;
    __syncthreads();
    if (threadIdx.x == 0) {
        atomicAdd(dacc, (double)(wsum[0] + wsum[1] + wsum[2] + wsum[3]));
    }
}

__global__ void rbc_finalize(const double* __restrict__ dacc, float* __restrict__ out) {
    const double N = (double)NB * TS * HH * WW;   // 12,582,912
    out[0] = (float)(dacc[0] / N);
}

extern "C" void kernel_launch(void* const* d_in, const int* in_sizes, int n_in,
                              void* d_out, int out_size, void* d_ws, size_t ws_size,
                              hipStream_t stream) {
    const float* pred = (const float*)d_in[0];
    double* dacc = (double*)d_ws;
    hipMemsetAsync(dacc, 0, sizeof(double), stream);

    const int nblocks = NB * NCH * 128;   // 1024 blocks x 256 threads
    rbc_loss_kernel<<<nblocks, 256, 0, stream>>>(pred, dacc);
    rbc_finalize<<<1, 1, 0, stream>>>(dacc, (float*)d_out);
}